// Round 1
// baseline (271.553 us; speedup 1.0000x reference)
//
#include <hip/hip_runtime.h>

#define DEVINL __device__ __forceinline__

// lower-tri packed index, requires i >= j
#define TIX(i, j) ((i) * ((i) + 1) / 2 + (j))
// symmetric access (i, j arbitrary) — resolves at compile time under full unroll
#define SYM(arr, i, j) ((i) >= (j) ? arr[TIX(i, j)] : arr[TIX(j, i)])

DEVINL void inv4(const float* m, float* inv) {
    // standard adjugate 4x4 inverse, row-major
    float s0 = m[0] * m[5] - m[1] * m[4];
    float s1 = m[0] * m[6] - m[2] * m[4];
    float s2 = m[0] * m[7] - m[3] * m[4];
    float s3 = m[1] * m[6] - m[2] * m[5];
    float s4 = m[1] * m[7] - m[3] * m[5];
    float s5 = m[2] * m[7] - m[3] * m[6];
    float c5 = m[10] * m[15] - m[11] * m[14];
    float c4 = m[9] * m[15] - m[11] * m[13];
    float c3 = m[9] * m[14] - m[10] * m[13];
    float c2 = m[8] * m[15] - m[11] * m[12];
    float c1 = m[8] * m[14] - m[10] * m[12];
    float c0 = m[8] * m[13] - m[9] * m[12];
    float det = s0 * c5 - s1 * c4 + s2 * c3 + s3 * c2 - s4 * c1 + s5 * c0;
    float id = 1.0f / det;
    inv[0]  = ( m[5] * c5 - m[6] * c4 + m[7] * c3) * id;
    inv[1]  = (-m[1] * c5 + m[2] * c4 - m[3] * c3) * id;
    inv[2]  = ( m[13] * s5 - m[14] * s4 + m[15] * s3) * id;
    inv[3]  = (-m[9] * s5 + m[10] * s4 - m[11] * s3) * id;
    inv[4]  = (-m[4] * c5 + m[6] * c2 - m[7] * c1) * id;
    inv[5]  = ( m[0] * c5 - m[2] * c2 + m[3] * c1) * id;
    inv[6]  = (-m[12] * s5 + m[14] * s2 - m[15] * s1) * id;
    inv[7]  = ( m[8] * s5 - m[10] * s2 + m[11] * s1) * id;
    inv[8]  = ( m[4] * c4 - m[5] * c2 + m[7] * c0) * id;
    inv[9]  = (-m[0] * c4 + m[1] * c2 - m[3] * c0) * id;
    inv[10] = ( m[12] * s4 - m[13] * s2 + m[15] * s0) * id;
    inv[11] = (-m[8] * s4 + m[9] * s2 - m[11] * s0) * id;
    inv[12] = (-m[4] * c3 + m[5] * c1 - m[6] * c0) * id;
    inv[13] = ( m[0] * c3 - m[1] * c1 + m[2] * c0) * id;
    inv[14] = (-m[12] * s3 + m[13] * s1 - m[14] * s0) * id;
    inv[15] = ( m[8] * s3 - m[9] * s1 + m[10] * s0) * id;
}

__global__ __launch_bounds__(256) void ekf_kernel(
    const float* __restrict__ meas,   // (B,4)
    const float* __restrict__ state,  // (B,8)
    const float* __restrict__ Pin,    // (B,8,8) symmetric
    const float* __restrict__ Fin,    // (B,8,8)
    const float* __restrict__ Hin,    // (B,4,8)
    const float* __restrict__ pnin,   // (B,36) tril of 8x8
    const float* __restrict__ mnin,   // (B,10) tril of 4x4
    float* __restrict__ out_pred,     // (B,4)
    float* __restrict__ out_state,    // (B,8)
    float* __restrict__ out_cov,      // (B,8,8)
    int B)
{
    const int b = blockIdx.x * blockDim.x + threadIdx.x;
    if (b >= B) return;

    // ---------- Q = Lq Lq^T (packed sym 36) ----------
    float Pn[36];  // will become new_state_cov; init with Q
    {
        float Lq[36];
        const float4* p4 = reinterpret_cast<const float4*>(pnin + (size_t)b * 36);
        #pragma unroll
        for (int i = 0; i < 9; ++i) {
            float4 v = p4[i];
            Lq[4 * i] = v.x; Lq[4 * i + 1] = v.y; Lq[4 * i + 2] = v.z; Lq[4 * i + 3] = v.w;
        }
        #pragma unroll
        for (int i = 0; i < 8; ++i)
            #pragma unroll
            for (int j = 0; j <= i; ++j) {
                float acc = 0.f;
                #pragma unroll
                for (int k = 0; k <= j; ++k)  // k <= min(i,j) == j
                    acc += Lq[TIX(i, k)] * Lq[TIX(j, k)];
                Pn[TIX(i, j)] = acc;
            }
    }

    // ---------- load F, P(sym), state ----------
    float Fm[64];
    {
        const float4* f4 = reinterpret_cast<const float4*>(Fin + (size_t)b * 64);
        #pragma unroll
        for (int i = 0; i < 16; ++i) {
            float4 v = f4[i];
            Fm[4 * i] = v.x; Fm[4 * i + 1] = v.y; Fm[4 * i + 2] = v.z; Fm[4 * i + 3] = v.w;
        }
    }
    float Ps[36];  // state_cov packed lower-tri (input is exactly symmetric)
    {
        const float4* p4 = reinterpret_cast<const float4*>(Pin + (size_t)b * 64);
        #pragma unroll
        for (int i = 0; i < 16; ++i) {
            float4 v = p4[i];
            const int row = i / 2, c0 = (i % 2) * 4;
            if (c0 + 0 <= row) Ps[TIX(row, c0 + 0)] = v.x;
            if (c0 + 1 <= row) Ps[TIX(row, c0 + 1)] = v.y;
            if (c0 + 2 <= row) Ps[TIX(row, c0 + 2)] = v.z;
            if (c0 + 3 <= row) Ps[TIX(row, c0 + 3)] = v.w;
        }
    }
    float s[8];
    {
        const float4* s4 = reinterpret_cast<const float4*>(state + (size_t)b * 8);
        float4 a = s4[0], c = s4[1];
        s[0] = a.x; s[1] = a.y; s[2] = a.z; s[3] = a.w;
        s[4] = c.x; s[5] = c.y; s[6] = c.z; s[7] = c.w;
    }

    // ---------- predict: ns = F s ----------
    float ns[8];
    #pragma unroll
    for (int i = 0; i < 8; ++i) {
        float acc = 0.f;
        #pragma unroll
        for (int j = 0; j < 8; ++j) acc += Fm[i * 8 + j] * s[j];
        ns[i] = acc;
    }

    // ---------- newP = F P F^T + Q ----------
    {
        float T[64];  // T = F * P
        #pragma unroll
        for (int i = 0; i < 8; ++i)
            #pragma unroll
            for (int k = 0; k < 8; ++k) {
                float acc = 0.f;
                #pragma unroll
                for (int j = 0; j < 8; ++j) acc += Fm[i * 8 + j] * SYM(Ps, j, k);
                T[i * 8 + k] = acc;
            }
        #pragma unroll
        for (int i = 0; i < 8; ++i)
            #pragma unroll
            for (int l = 0; l <= i; ++l) {
                float acc = Pn[TIX(i, l)];  // starts at Q
                #pragma unroll
                for (int k = 0; k < 8; ++k) acc += T[i * 8 + k] * Fm[l * 8 + k];
                Pn[TIX(i, l)] = acc;
            }
    }
    // F, T, Ps, s dead here

    // ---------- load H, measurement, R ----------
    float Hm[32];
    {
        const float4* h4 = reinterpret_cast<const float4*>(Hin + (size_t)b * 32);
        #pragma unroll
        for (int i = 0; i < 8; ++i) {
            float4 v = h4[i];
            Hm[4 * i] = v.x; Hm[4 * i + 1] = v.y; Hm[4 * i + 2] = v.z; Hm[4 * i + 3] = v.w;
        }
    }
    float Rs[10];
    {
        float Lr[10];
        const float2* m2 = reinterpret_cast<const float2*>(mnin + (size_t)b * 10);
        #pragma unroll
        for (int i = 0; i < 5; ++i) {
            float2 v = m2[i];
            Lr[2 * i] = v.x; Lr[2 * i + 1] = v.y;
        }
        #pragma unroll
        for (int i = 0; i < 4; ++i)
            #pragma unroll
            for (int j = 0; j <= i; ++j) {
                float acc = 0.f;
                #pragma unroll
                for (int k = 0; k <= j; ++k)
                    acc += Lr[TIX(i, k)] * Lr[TIX(j, k)];
                Rs[TIX(i, j)] = acc;
            }
    }

    // ---------- prediction + residual ----------
    float pred[4], res[4];
    {
        float4 z = *reinterpret_cast<const float4*>(meas + (size_t)b * 4);
        const float zz[4] = {z.x, z.y, z.z, z.w};
        #pragma unroll
        for (int i = 0; i < 4; ++i) {
            float acc = 0.f;
            #pragma unroll
            for (int j = 0; j < 8; ++j) acc += Hm[i * 8 + j] * ns[j];
            pred[i] = acc;
            res[i] = zz[i] - acc;
        }
    }

    // ---------- HP = H * newP  (4x8); PHt = HP^T by symmetry ----------
    float HP[32];
    #pragma unroll
    for (int i = 0; i < 4; ++i)
        #pragma unroll
        for (int k = 0; k < 8; ++k) {
            float acc = 0.f;
            #pragma unroll
            for (int j = 0; j < 8; ++j) acc += Hm[i * 8 + j] * SYM(Pn, j, k);
            HP[i * 8 + k] = acc;
        }

    // ---------- S = HP H^T + R  -> inverse ----------
    float Si[16];
    {
        float Sf[16];
        #pragma unroll
        for (int i = 0; i < 4; ++i)
            #pragma unroll
            for (int l = 0; l < 4; ++l) {
                float acc = SYM(Rs, i, l);
                #pragma unroll
                for (int k = 0; k < 8; ++k) acc += HP[i * 8 + k] * Hm[l * 8 + k];
                Sf[i * 4 + l] = acc;
            }
        inv4(Sf, Si);
    }

    // ---------- K = PHt * Si  (8x4), PHt[i][k] = HP[k][i] ----------
    float K[32];
    #pragma unroll
    for (int i = 0; i < 8; ++i)
        #pragma unroll
        for (int j = 0; j < 4; ++j) {
            float acc = 0.f;
            #pragma unroll
            for (int k = 0; k < 4; ++k) acc += HP[k * 8 + i] * Si[k * 4 + j];
            K[i * 4 + j] = acc;
        }

    // ---------- outputs ----------
    float* op = out_pred + (size_t)b * 4;
    *reinterpret_cast<float4*>(op) = make_float4(pred[0], pred[1], pred[2], pred[3]);

    float us[8];
    #pragma unroll
    for (int i = 0; i < 8; ++i) {
        float acc = ns[i];
        #pragma unroll
        for (int j = 0; j < 4; ++j) acc += K[i * 4 + j] * res[j];
        us[i] = acc;
    }
    float* osp = out_state + (size_t)b * 8;
    *reinterpret_cast<float4*>(osp + 0) = make_float4(us[0], us[1], us[2], us[3]);
    *reinterpret_cast<float4*>(osp + 4) = make_float4(us[4], us[5], us[6], us[7]);

    // ---------- upd_cov = (I - K H) newP, row by row ----------
    float* ocp = out_cov + (size_t)b * 64;
    #pragma unroll
    for (int i = 0; i < 8; ++i) {
        float Arow[8];
        #pragma unroll
        for (int j = 0; j < 8; ++j) {
            float acc = (i == j) ? 1.f : 0.f;
            #pragma unroll
            for (int k = 0; k < 4; ++k) acc -= K[i * 4 + k] * Hm[k * 8 + j];
            Arow[j] = acc;
        }
        float orow[8];
        #pragma unroll
        for (int j = 0; j < 8; ++j) {
            float acc = 0.f;
            #pragma unroll
            for (int k = 0; k < 8; ++k) acc += Arow[k] * SYM(Pn, k, j);
            orow[j] = acc;
        }
        *reinterpret_cast<float4*>(ocp + i * 8 + 0) = make_float4(orow[0], orow[1], orow[2], orow[3]);
        *reinterpret_cast<float4*>(ocp + i * 8 + 4) = make_float4(orow[4], orow[5], orow[6], orow[7]);
    }
}

extern "C" void kernel_launch(void* const* d_in, const int* in_sizes, int n_in,
                              void* d_out, int out_size, void* d_ws, size_t ws_size,
                              hipStream_t stream) {
    const float* meas  = (const float*)d_in[0];
    const float* state = (const float*)d_in[1];
    const float* Pin   = (const float*)d_in[2];
    const float* Fin   = (const float*)d_in[3];
    const float* Hin   = (const float*)d_in[4];
    const float* pn    = (const float*)d_in[5];
    const float* mn    = (const float*)d_in[6];

    const int B = in_sizes[1] / 8;  // state is (B, 8)

    float* out = (float*)d_out;
    float* out_pred  = out;                       // B*4
    float* out_state = out + (size_t)B * 4;       // B*8
    float* out_cov   = out + (size_t)B * 12;      // B*64

    dim3 block(256);
    dim3 grid((B + 255) / 256);
    ekf_kernel<<<grid, block, 0, stream>>>(meas, state, Pin, Fin, Hin, pn, mn,
                                           out_pred, out_state, out_cov, B);
}